// Round 1
// baseline (3341.421 us; speedup 1.0000x reference)
//
#include <hip/hip_runtime.h>
#include <hip/hip_cooperative_groups.h>

namespace cg = cooperative_groups;

// ---------- types ----------
using bf16x8 = __attribute__((ext_vector_type(8))) __bf16;
using f32x4  = __attribute__((ext_vector_type(4))) float;

__device__ __forceinline__ f32x4 mfma16(bf16x8 a, bf16x8 b, f32x4 c) {
    return __builtin_amdgcn_mfma_f32_16x16x32_bf16(a, b, c, 0, 0, 0);
}

__device__ __forceinline__ bf16x8 cvt8v(float4 u, float4 v) {
    bf16x8 r;
    r[0] = (__bf16)u.x; r[1] = (__bf16)u.y; r[2] = (__bf16)u.z; r[3] = (__bf16)u.w;
    r[4] = (__bf16)v.x; r[5] = (__bf16)v.y; r[6] = (__bf16)v.z; r[7] = (__bf16)v.w;
    return r;
}

// ---------- constants ----------
#define HID   1024
#define B3    3072
#define NB    64      // batch
#define TENC  40
#define TDEC  27
#define TTOT  67      // TENC + TDEC
#define VOC   32000
#define HB    65536   // NB * HID

// ---------- zero init of h1(-1), h2(-1) slabs ----------
__global__ __launch_bounds__(256) void zero_h(__bf16* __restrict__ h1, __bf16* __restrict__ h2) {
    int i = blockIdx.x * 256 + threadIdx.x;   // 65536 threads
    h1[i] = (__bf16)0.f;
    h2[i] = (__bf16)0.f;
}

// ---------- word gather: words[t*64+b][:] = bf16(emb[tgt[b][t]][:]) ----------
__global__ __launch_bounds__(64) void gather_words(const float* __restrict__ emb,
                                                   const int* __restrict__ tgt,
                                                   __bf16* __restrict__ words) {
    int row = blockIdx.x;            // 0..1727  = t*64 + b
    int b = row & 63, t = row >> 6;
    int idx = tgt[b * 28 + t];
    const float* src = emb + (size_t)idx * 512 + threadIdx.x * 8;
    float4 u = *(const float4*)src;
    float4 v = *(const float4*)(src + 4);
    *(bf16x8*)(words + (size_t)row * 512 + threadIdx.x * 8) = cvt8v(u, v);
}

// ---------- tiled GEMM: C = A(MxK) @ B(NxK)^T + bias  (used for gi1, wproj) ----------
template <typename TA, bool OUTBF>
__global__ __launch_bounds__(256) void gemm_bt(
    const TA* __restrict__ A, int lda,
    const float* __restrict__ Bw, int ldb,
    const float* __restrict__ bias,
    void* __restrict__ Cout, int ldc,
    int K, int mdiv, int ms1, int ms2)
{
    __shared__ __align__(16) __bf16 As[64][40];
    __shared__ __align__(16) __bf16 Bs[64][40];
    const int tid  = threadIdx.x;
    const int m0   = blockIdx.x * 64;
    const int n0   = blockIdx.y * 64;
    const int srow = tid >> 2;
    const int sseg = (tid & 3) * 8;
    const TA*    ga = A  + (size_t)(m0 + srow) * lda + sseg;
    const float* gb = Bw + (size_t)(n0 + srow) * ldb + sseg;
    const int lane  = tid & 63, wave = tid >> 6;
    const int wm    = (wave >> 1) * 32, wn = (wave & 1) * 32;
    const int row15 = lane & 15, quad = lane >> 4;

    f32x4 acc[2][2] = {};
    for (int k = 0; k < K; k += 32) {
        __syncthreads();
        if constexpr (__is_same(TA, float)) {
            float4 u = *(const float4*)(ga + k);
            float4 v = *(const float4*)(ga + k + 4);
            *(bf16x8*)&As[srow][sseg] = cvt8v(u, v);
        } else {
            *(bf16x8*)&As[srow][sseg] = *(const bf16x8*)(ga + k);
        }
        {
            float4 u = *(const float4*)(gb + k);
            float4 v = *(const float4*)(gb + k + 4);
            *(bf16x8*)&Bs[srow][sseg] = cvt8v(u, v);
        }
        __syncthreads();
        bf16x8 a0 = *(const bf16x8*)&As[wm + row15][quad * 8];
        bf16x8 a1 = *(const bf16x8*)&As[wm + 16 + row15][quad * 8];
        bf16x8 b0 = *(const bf16x8*)&Bs[wn + row15][quad * 8];
        bf16x8 b1 = *(const bf16x8*)&Bs[wn + 16 + row15][quad * 8];
        acc[0][0] = mfma16(a0, b0, acc[0][0]);
        acc[0][1] = mfma16(a0, b1, acc[0][1]);
        acc[1][0] = mfma16(a1, b0, acc[1][0]);
        acc[1][1] = mfma16(a1, b1, acc[1][1]);
    }
    #pragma unroll
    for (int mt = 0; mt < 2; ++mt)
        #pragma unroll
        for (int nt = 0; nt < 2; ++nt)
            #pragma unroll
            for (int i = 0; i < 4; ++i) {
                int m = m0 + wm + mt * 16 + quad * 4 + i;
                int n = n0 + wn + nt * 16 + row15;
                int orow = (m % mdiv) * ms1 + (m / mdiv) * ms2;
                float v = acc[mt][nt][i] + bias[n];
                if constexpr (OUTBF)
                    ((__bf16*)Cout)[(size_t)orow * ldc + n] = (__bf16)v;
                else
                    ((float*)Cout)[(size_t)orow * ldc + n] = v;
            }
}

// ================= persistent GRU chain =================
// 192 blocks, 3 groups of 64. Block (grp, s) owns hidden cols [s*16, s*16+16).
//   grp 0: h1 chain with Whh1   (phase p computes h1(p))
//   grp 1: gi2(t) = h1(t) @ Wih2[:, :1024]^T   (phase p computes t = p-1)
//   grp 2: h2 chain with Whh2   (phase p computes t = p-2)
// Slab convention: h1s/h2s slab (t+1) holds h(t); slab 0 = zeros.
// gi2 is a 4-deep ring of 64x3072 f32 slabs (index t & 3), NO biases included.

// Weight slice (48 rows x 1024 K) -> LDS as [k8 in 0..128)[r48 in 0..48) tiles of 8 bf16.
// r48 = gate*16 + jj maps to source row gate*1024 + j0 + jj.
__device__ __forceinline__ void load_wslice(
    __bf16* W, int grp, int j0,
    const float* __restrict__ Whh1, const float* __restrict__ Whh2,
    const float* __restrict__ Wih2)
{
    const int tid = threadIdx.x;
    const float* src = (grp == 0) ? Whh1 : (grp == 1) ? Wih2 : Whh2;
    const int ld = (grp == 1) ? 1536 : 1024;
    #pragma unroll 4
    for (int i = 0; i < 24; ++i) {
        int tile = i * 256 + tid;               // 6144 tiles
        int r48 = tile >> 7, k8 = tile & 127;
        int srow = (r48 >> 4) * HID + j0 + (r48 & 15);
        const float* pp = src + (size_t)srow * ld + k8 * 8;
        float4 u = *(const float4*)pp;
        float4 v = *(const float4*)(pp + 4);
        *(bf16x8*)&W[(size_t)(k8 * 48 + r48) * 8] = cvt8v(u, v);
    }
}

__device__ __forceinline__ void chain_phase(
    int p, int grp, int j0, const __bf16* __restrict__ W,
    const float* __restrict__ bhh1, const float* __restrict__ bih1,
    const float* __restrict__ bhh2, const float* __restrict__ bih2,
    const __bf16* __restrict__ gi1, const __bf16* __restrict__ wproj,
    __bf16* __restrict__ h1s, __bf16* __restrict__ h2s, float* __restrict__ gi2)
{
    const int t = p - (grp == 1 ? 1 : grp == 2 ? 2 : 0);
    if (t < 0 || t >= TTOT) return;
    const int tid = threadIdx.x;
    const int lane = tid & 63, wave = tid >> 6;
    const int row15 = lane & 15, quad = lane >> 4;
    const int j = j0 + row15;

    const __bf16* Ab = (grp == 0) ? h1s + (size_t)t * HB
                     : (grp == 1) ? h1s + (size_t)(t + 1) * HB
                                  : h2s + (size_t)t * HB;

    f32x4 a0 = {}, a1 = {}, a2 = {};
    const __bf16* ap = Ab + (size_t)(wave * 16 + row15) * HID + quad * 8;
    #pragma unroll 4
    for (int k = 0; k < HID; k += 32) {
        bf16x8 av = *(const bf16x8*)(ap + k);
        const __bf16* wp = W + (size_t)(((k >> 3) + quad) * 48 + row15) * 8;
        a0 = mfma16(av, *(const bf16x8*)(wp),       a0);
        a1 = mfma16(av, *(const bf16x8*)(wp + 128), a1);   // +16 rows
        a2 = mfma16(av, *(const bf16x8*)(wp + 256), a2);   // +32 rows
    }

    if (grp == 1) {
        // raw gi2 (no bias); slab ring index t&3
        float* op = gi2 + ((size_t)(t & 3) * NB + wave * 16 + quad * 4) * B3 + j;
        #pragma unroll
        for (int i = 0; i < 4; ++i) {
            op[(size_t)i * B3]           = a0[i];
            op[(size_t)i * B3 + HID]     = a1[i];
            op[(size_t)i * B3 + 2 * HID] = a2[i];
        }
        return;
    }

    const float* bh = (grp == 0) ? bhh1 : bhh2;
    const float b0 = bh[j], b1 = bh[HID + j], b2 = bh[2 * HID + j];
    __bf16* ho_ptr = ((grp == 0) ? h1s : h2s) + (size_t)(t + 1) * HB;

    #pragma unroll
    for (int i = 0; i < 4; ++i) {
        const int m = wave * 16 + quad * 4 + i;
        float gir, giz, gin;
        if (grp == 0) {
            if (t < TENC) {   // encoder: gi1 includes bih1
                const __bf16* pp = gi1 + ((size_t)t * NB + m) * B3 + j;
                gir = (float)pp[0]; giz = (float)pp[HID]; gin = (float)pp[2 * HID];
            } else {          // decoder: x = 0 -> gi = bih1
                gir = bih1[j]; giz = bih1[HID + j]; gin = bih1[2 * HID + j];
            }
        } else {              // grp 2
            const float* gp = gi2 + ((size_t)(t & 3) * NB + m) * B3 + j;
            gir = gp[0]; giz = gp[HID]; gin = gp[2 * HID];
            if (t < TENC) {   // encoder: word part is zero -> add bih2
                gir += bih2[j]; giz += bih2[HID + j]; gin += bih2[2 * HID + j];
            } else {          // decoder: wproj includes word part + bih2
                const __bf16* pp = wproj + ((size_t)(t - TENC) * NB + m) * B3 + j;
                gir += (float)pp[0]; giz += (float)pp[HID]; gin += (float)pp[2 * HID];
            }
        }
        float ghr = a0[i] + b0, ghz = a1[i] + b1, ghn = a2[i] + b2;
        float r = 1.f / (1.f + expf(-(gir + ghr)));
        float z = 1.f / (1.f + expf(-(giz + ghz)));
        float n = tanhf(gin + r * ghn);
        float ho = (float)Ab[(size_t)m * HID + j];
        float hv = (1.f - z) * n + z * ho;
        ho_ptr[(size_t)m * HID + j] = (__bf16)hv;
    }
}

__global__ __launch_bounds__(256, 1) void gru_chain(
    const float* __restrict__ Whh1, const float* __restrict__ Whh2, const float* __restrict__ Wih2,
    const float* __restrict__ bhh1, const float* __restrict__ bih1,
    const float* __restrict__ bhh2, const float* __restrict__ bih2,
    const __bf16* __restrict__ gi1, const __bf16* __restrict__ wproj,
    __bf16* __restrict__ h1s, __bf16* __restrict__ h2s, float* __restrict__ gi2)
{
    __shared__ __align__(16) __bf16 W[48 * HID];   // 96 KiB -> 1 block/CU
    const int grp = blockIdx.x >> 6;
    const int j0  = (blockIdx.x & 63) * 16;
    load_wslice(W, grp, j0, Whh1, Whh2, Wih2);
    __syncthreads();
    cg::grid_group g = cg::this_grid();
    for (int p = 0; p < TTOT + 2; ++p) {
        chain_phase(p, grp, j0, W, bhh1, bih1, bhh2, bih2, gi1, wproj, h1s, h2s, gi2);
        g.sync();
    }
}

// Fallback (no cooperative launch): one launch per phase; kernel boundary = grid sync.
__global__ __launch_bounds__(256, 1) void gru_chain_phase(
    int p,
    const float* __restrict__ Whh1, const float* __restrict__ Whh2, const float* __restrict__ Wih2,
    const float* __restrict__ bhh1, const float* __restrict__ bih1,
    const float* __restrict__ bhh2, const float* __restrict__ bih2,
    const __bf16* __restrict__ gi1, const __bf16* __restrict__ wproj,
    __bf16* __restrict__ h1s, __bf16* __restrict__ h2s, float* __restrict__ gi2)
{
    __shared__ __align__(16) __bf16 W[48 * HID];
    const int grp = blockIdx.x >> 6;
    const int j0  = (blockIdx.x & 63) * 16;
    load_wslice(W, grp, j0, Whh1, Whh2, Wih2);
    __syncthreads();
    chain_phase(p, grp, j0, W, bhh1, bih1, bhh2, bih2, gi1, wproj, h1s, h2s, gi2);
}

// ================= logits GEMM, Wout panel resident in LDS =================
// 500 blocks; block stages its 64-col Wout panel (bf16, [k8][col] tiles) into
// 128 KiB LDS ONCE, then sweeps all 27 m-tiles (3 per acc group to cut LDS B-reads 3x).
// C row remap: A row m = t*64+b  ->  out row b*27+t.
__global__ __launch_bounds__(256, 1) void out_gemm(
    const __bf16* __restrict__ A,   // 1728 x 1024 (decoder h2 slabs)
    const float* __restrict__ Bw,   // Wout 32000 x 1024
    const float* __restrict__ bias, // bout
    float* __restrict__ C)          // 1728 x 32000
{
    __shared__ __align__(16) __bf16 Bs[128 * 64 * 8];   // 128 KiB
    const int tid = threadIdx.x;
    const int n0 = blockIdx.x * 64;
    {
        const int col = tid >> 2, seg = tid & 3;        // 4 threads/col, coalesced per-thread streams
        const float* src = Bw + (size_t)(n0 + col) * HID + seg * 256;
        for (int i = 0; i < 32; ++i) {
            float4 u = *(const float4*)(src + i * 8);
            float4 v = *(const float4*)(src + i * 8 + 4);
            *(bf16x8*)&Bs[(size_t)((seg * 32 + i) * 64 + col) * 8] = cvt8v(u, v);
        }
    }
    __syncthreads();
    const int lane = tid & 63, wave = tid >> 6;
    const int row15 = lane & 15, quad = lane >> 4;
    float bn[4];
    #pragma unroll
    for (int ns = 0; ns < 4; ++ns) bn[ns] = bias[n0 + ns * 16 + row15];

    for (int mg = 0; mg < 9; ++mg) {     // 9 groups x 3 m-tiles = 27
        f32x4 acc[3][4] = {};
        const __bf16* ap = A + (size_t)(mg * 192 + wave * 16 + row15) * HID + quad * 8;
        for (int k = 0; k < HID; k += 32) {
            const __bf16* bp = &Bs[(size_t)(((k >> 3) + quad) * 64 + row15) * 8];
            bf16x8 b0 = *(const bf16x8*)(bp);
            bf16x8 b1 = *(const bf16x8*)(bp + 128);
            bf16x8 b2 = *(const bf16x8*)(bp + 256);
            bf16x8 b3 = *(const bf16x8*)(bp + 384);
            #pragma unroll
            for (int mi = 0; mi < 3; ++mi) {
                bf16x8 av = *(const bf16x8*)(ap + (size_t)mi * 64 * HID + k);
                acc[mi][0] = mfma16(av, b0, acc[mi][0]);
                acc[mi][1] = mfma16(av, b1, acc[mi][1]);
                acc[mi][2] = mfma16(av, b2, acc[mi][2]);
                acc[mi][3] = mfma16(av, b3, acc[mi][3]);
            }
        }
        #pragma unroll
        for (int mi = 0; mi < 3; ++mi) {
            const int mt = mg * 3 + mi;
            #pragma unroll
            for (int ns = 0; ns < 4; ++ns)
                #pragma unroll
                for (int i = 0; i < 4; ++i) {
                    const int b = wave * 16 + quad * 4 + i;
                    C[(size_t)(b * TDEC + mt) * VOC + n0 + ns * 16 + row15] = acc[mi][ns][i] + bn[ns];
                }
        }
    }
}

// ---------- in-place row log-softmax over 32000 f32 cols ----------
__global__ __launch_bounds__(256) void logsoftmax_rows(float* __restrict__ out) {
    const int r = blockIdx.x;
    float* p = out + (size_t)r * VOC;
    const int tid = threadIdx.x;
    const int lane = tid & 63, wid = tid >> 6;
    __shared__ float red[4];
    __shared__ float bc[2];

    float mx = -3.0e38f;
    for (int c = tid; c < VOC / 4; c += 256) {
        float4 v = ((const float4*)p)[c];
        mx = fmaxf(mx, fmaxf(fmaxf(v.x, v.y), fmaxf(v.z, v.w)));
    }
    #pragma unroll
    for (int o = 32; o > 0; o >>= 1) mx = fmaxf(mx, __shfl_down(mx, o));
    if (lane == 0) red[wid] = mx;
    __syncthreads();
    if (tid == 0) bc[0] = fmaxf(fmaxf(red[0], red[1]), fmaxf(red[2], red[3]));
    __syncthreads();
    mx = bc[0];

    float s = 0.f;
    for (int c = tid; c < VOC / 4; c += 256) {
        float4 v = ((const float4*)p)[c];
        s += expf(v.x - mx) + expf(v.y - mx) + expf(v.z - mx) + expf(v.w - mx);
    }
    #pragma unroll
    for (int o = 32; o > 0; o >>= 1) s += __shfl_down(s, o);
    if (lane == 0) red[wid] = s;
    __syncthreads();
    if (tid == 0) bc[1] = mx + logf(red[0] + red[1] + red[2] + red[3]);
    __syncthreads();
    const float C = bc[1];

    for (int c = tid; c < VOC / 4; c += 256) {
        float4 v = ((const float4*)p)[c];
        v.x -= C; v.y -= C; v.z -= C; v.w -= C;
        ((float4*)p)[c] = v;
    }
}

// ---------- launch ----------
extern "C" void kernel_launch(void* const* d_in, const int* in_sizes, int n_in,
                              void* d_out, int out_size, void* d_ws, size_t ws_size,
                              hipStream_t stream) {
    const float* vid  = (const float*)d_in[0];
    const int*   tgt  = (const int*)d_in[1];
    const float* emb  = (const float*)d_in[2];
    const float* Wih1 = (const float*)d_in[3];
    const float* Whh1 = (const float*)d_in[4];
    const float* bih1 = (const float*)d_in[5];
    const float* bhh1 = (const float*)d_in[6];
    const float* Wih2 = (const float*)d_in[7];
    const float* Whh2 = (const float*)d_in[8];
    const float* bih2 = (const float*)d_in[9];
    const float* bhh2 = (const float*)d_in[10];
    const float* Wout = (const float*)d_in[11];
    const float* bout = (const float*)d_in[12];
    float* out = (float*)d_out;

    char* w = (char*)d_ws;
    __bf16* h1s   = (__bf16*)w; w += (size_t)68 * HB * 2;           // 68 slabs (slab0 = zeros)
    __bf16* h2s   = (__bf16*)w; w += (size_t)68 * HB * 2;
    float*  gi2   = (float*)w;  w += (size_t)4 * NB * B3 * 4;       // 4-deep ring, f32
    __bf16* gi1   = (__bf16*)w; w += (size_t)TENC * NB * B3 * 2;    // 40x64x3072
    __bf16* wproj = (__bf16*)w; w += (size_t)TDEC * NB * B3 * 2;    // 27x64x3072 (incl. bih2)
    __bf16* words = (__bf16*)w; w += (size_t)TDEC * NB * 512 * 2;

    zero_h<<<256, 256, 0, stream>>>(h1s, h2s);

    // gi1[t*64+b][:] = vid[b][t][:] @ Wih1^T + bih1   (m=b*40+t -> orow=(m%40)*64+m/40)
    gemm_bt<float, true><<<dim3(TENC, 48), 256, 0, stream>>>(
        vid, 2048, Wih1, 2048, bih1, gi1, B3, 2048, TENC, 64, 1);

    gather_words<<<TDEC * NB, 64, 0, stream>>>(emb, tgt, words);

    // wproj[t*64+b][:] = words row @ Wih2[:,1024:]^T + bih2
    gemm_bt<__bf16, true><<<dim3(TDEC, 48), 256, 0, stream>>>(
        words, 512, Wih2 + 1024, 1536, bih2, wproj, B3, 512, 1 << 30, 1, 0);

    static int coop = -1;
    if (coop < 0) {
        int dev = 0; (void)hipGetDevice(&dev);
        int v = 0;
        if (hipDeviceGetAttribute(&v, hipDeviceAttributeCooperativeLaunch, dev) != hipSuccess) v = 0;
        coop = v;
    }
    bool launched = false;
    if (coop) {
        void* cargs[] = {(void*)&Whh1, (void*)&Whh2, (void*)&Wih2,
                         (void*)&bhh1, (void*)&bih1, (void*)&bhh2, (void*)&bih2,
                         (void*)&gi1, (void*)&wproj,
                         (void*)&h1s, (void*)&h2s, (void*)&gi2};
        launched = (hipLaunchCooperativeKernel((void*)gru_chain, dim3(192), dim3(256),
                                               cargs, 0, stream) == hipSuccess);
    }
    if (!launched) {
        for (int p = 0; p < TTOT + 2; ++p)
            gru_chain_phase<<<192, 256, 0, stream>>>(p, Whh1, Whh2, Wih2,
                                                     bhh1, bih1, bhh2, bih2,
                                                     gi1, wproj, h1s, h2s, gi2);
    }

    // logits: decoder h2 slabs (41..67) @ Wout^T + bout -> out rows b*27+t
    out_gemm<<<500, 256, 0, stream>>>(h2s + (size_t)41 * HB, Wout, bout, out);

    logsoftmax_rows<<<TDEC * NB, 256, 0, stream>>>(out);
}

// Round 2
// 3131.442 us; speedup vs baseline: 1.0671x; 1.0671x over previous
//
#include <hip/hip_runtime.h>
#include <hip/hip_cooperative_groups.h>

namespace cg = cooperative_groups;

// ---------- types ----------
using bf16x8 = __attribute__((ext_vector_type(8))) __bf16;
using f32x4  = __attribute__((ext_vector_type(4))) float;

__device__ __forceinline__ f32x4 mfma16(bf16x8 a, bf16x8 b, f32x4 c) {
    return __builtin_amdgcn_mfma_f32_16x16x32_bf16(a, b, c, 0, 0, 0);
}

__device__ __forceinline__ bf16x8 cvt8v(float4 u, float4 v) {
    bf16x8 r;
    r[0] = (__bf16)u.x; r[1] = (__bf16)u.y; r[2] = (__bf16)u.z; r[3] = (__bf16)u.w;
    r[4] = (__bf16)v.x; r[5] = (__bf16)v.y; r[6] = (__bf16)v.z; r[7] = (__bf16)v.w;
    return r;
}

// ---------- constants ----------
#define HID   1024
#define B3    3072
#define NB    64      // batch
#define TENC  40
#define TDEC  27
#define TTOT  67      // TENC + TDEC
#define VOC   32000
#define HB    65536   // NB * HID
#define NFLAG 8192

// ---------- flag sync primitives (device-scope) ----------
__device__ __forceinline__ void block_release(int* f) {
    __syncthreads();                       // all stores of this block complete (vmcnt drained)
    if (threadIdx.x == 0) {
        __threadfence();                   // make them agent-visible
        __hip_atomic_fetch_add(f, 1, __ATOMIC_RELEASE, __HIP_MEMORY_SCOPE_AGENT);
    }
}
__device__ __forceinline__ void block_wait(int* f, int tgt) {
    if (threadIdx.x == 0) {
        while (__hip_atomic_load(f, __ATOMIC_ACQUIRE, __HIP_MEMORY_SCOPE_AGENT) < tgt)
            __builtin_amdgcn_s_sleep(1);
        __threadfence();                   // invalidate stale cached lines before reads
    }
    __syncthreads();
}

// ---------- zero init of h1(-1), h2(-1) slabs + sync flags ----------
__global__ __launch_bounds__(256) void zero_h(__bf16* __restrict__ h1, __bf16* __restrict__ h2,
                                              int* __restrict__ flags) {
    int i = blockIdx.x * 256 + threadIdx.x;   // 65536 threads
    h1[i] = (__bf16)0.f;
    h2[i] = (__bf16)0.f;
    if (i < NFLAG) flags[i] = 0;
}

// ---------- word gather: words[t*64+b][:] = bf16(emb[tgt[b][t]][:]) ----------
__global__ __launch_bounds__(64) void gather_words(const float* __restrict__ emb,
                                                   const int* __restrict__ tgt,
                                                   __bf16* __restrict__ words) {
    int row = blockIdx.x;            // 0..1727  = t*64 + b
    int b = row & 63, t = row >> 6;
    int idx = tgt[b * 28 + t];
    const float* src = emb + (size_t)idx * 512 + threadIdx.x * 8;
    float4 u = *(const float4*)src;
    float4 v = *(const float4*)(src + 4);
    *(bf16x8*)(words + (size_t)row * 512 + threadIdx.x * 8) = cvt8v(u, v);
}

// ---------- tiled GEMM: C = A(MxK) @ B(NxK)^T + bias  (used for gi1, wproj) ----------
template <typename TA, bool OUTBF>
__global__ __launch_bounds__(256) void gemm_bt(
    const TA* __restrict__ A, int lda,
    const float* __restrict__ Bw, int ldb,
    const float* __restrict__ bias,
    void* __restrict__ Cout, int ldc,
    int K, int mdiv, int ms1, int ms2)
{
    __shared__ __align__(16) __bf16 As[64][40];
    __shared__ __align__(16) __bf16 Bs[64][40];
    const int tid  = threadIdx.x;
    const int m0   = blockIdx.x * 64;
    const int n0   = blockIdx.y * 64;
    const int srow = tid >> 2;
    const int sseg = (tid & 3) * 8;
    const TA*    ga = A  + (size_t)(m0 + srow) * lda + sseg;
    const float* gb = Bw + (size_t)(n0 + srow) * ldb + sseg;
    const int lane  = tid & 63, wave = tid >> 6;
    const int wm    = (wave >> 1) * 32, wn = (wave & 1) * 32;
    const int row15 = lane & 15, quad = lane >> 4;

    f32x4 acc[2][2] = {};
    for (int k = 0; k < K; k += 32) {
        __syncthreads();
        if constexpr (__is_same(TA, float)) {
            float4 u = *(const float4*)(ga + k);
            float4 v = *(const float4*)(ga + k + 4);
            *(bf16x8*)&As[srow][sseg] = cvt8v(u, v);
        } else {
            *(bf16x8*)&As[srow][sseg] = *(const bf16x8*)(ga + k);
        }
        {
            float4 u = *(const float4*)(gb + k);
            float4 v = *(const float4*)(gb + k + 4);
            *(bf16x8*)&Bs[srow][sseg] = cvt8v(u, v);
        }
        __syncthreads();
        bf16x8 a0 = *(const bf16x8*)&As[wm + row15][quad * 8];
        bf16x8 a1 = *(const bf16x8*)&As[wm + 16 + row15][quad * 8];
        bf16x8 b0 = *(const bf16x8*)&Bs[wn + row15][quad * 8];
        bf16x8 b1 = *(const bf16x8*)&Bs[wn + 16 + row15][quad * 8];
        acc[0][0] = mfma16(a0, b0, acc[0][0]);
        acc[0][1] = mfma16(a0, b1, acc[0][1]);
        acc[1][0] = mfma16(a1, b0, acc[1][0]);
        acc[1][1] = mfma16(a1, b1, acc[1][1]);
    }
    #pragma unroll
    for (int mt = 0; mt < 2; ++mt)
        #pragma unroll
        for (int nt = 0; nt < 2; ++nt)
            #pragma unroll
            for (int i = 0; i < 4; ++i) {
                int m = m0 + wm + mt * 16 + quad * 4 + i;
                int n = n0 + wn + nt * 16 + row15;
                int orow = (m % mdiv) * ms1 + (m / mdiv) * ms2;
                float v = acc[mt][nt][i] + bias[n];
                if constexpr (OUTBF)
                    ((__bf16*)Cout)[(size_t)orow * ldc + n] = (__bf16)v;
                else
                    ((float*)Cout)[(size_t)orow * ldc + n] = v;
            }
}

// ================= persistent GRU chain (flag-paced pipeline) =================
// 192 blocks, 3 groups of 64. Block (grp, jb) owns hidden cols [jb*16, jb*16+16).
//   grp 0: h1 chain with Whh1       (step t: reads h1 slab t, writes slab t+1)
//   grp 1: gi2(t) = h1(t) @ Wih2[:, :1024]^T  -> f32 ring slot t&3
//   grp 2: h2 chain with Whh2       (step t: reads h2 slab t + gi2 slot, writes slab t+1)
// Flags: c_h1[t], c_h2[t] = #blocks finished (64-counters); g2f[t*64+jb] per-block gi2 flag.
// gi2 dependency is 1-to-1 in jb (grp2 block jb reads only cols written by grp1 block jb).
// Ring backpressure: grp1 at t>=4 waits c_h2[t-4]==64 (slot t&3 free).

__device__ __forceinline__ void load_wslice(
    __bf16* W, int grp, int j0,
    const float* __restrict__ Whh1, const float* __restrict__ Whh2,
    const float* __restrict__ Wih2)
{
    const int tid = threadIdx.x;
    const float* src = (grp == 0) ? Whh1 : (grp == 1) ? Wih2 : Whh2;
    const int ld = (grp == 1) ? 1536 : 1024;
    #pragma unroll 4
    for (int i = 0; i < 24; ++i) {
        int tile = i * 256 + tid;               // 6144 tiles
        int r48 = tile >> 7, k8 = tile & 127;
        int srow = (r48 >> 4) * HID + j0 + (r48 & 15);
        const float* pp = src + (size_t)srow * ld + k8 * 8;
        float4 u = *(const float4*)pp;
        float4 v = *(const float4*)(pp + 4);
        *(bf16x8*)&W[(size_t)(k8 * 48 + r48) * 8] = cvt8v(u, v);
    }
}

__device__ __forceinline__ void chain_step(
    int grp, int t, int jb, const __bf16* __restrict__ W,
    const float* __restrict__ bhh1, const float* __restrict__ bih1,
    const float* __restrict__ bhh2, const float* __restrict__ bih2,
    const __bf16* __restrict__ gi1, const __bf16* __restrict__ wproj,
    __bf16* __restrict__ h1s, __bf16* __restrict__ h2s, float* __restrict__ gi2,
    int* __restrict__ c_h1, int* __restrict__ c_h2, int* __restrict__ g2f)
{
    const int tid = threadIdx.x;
    const int lane = tid & 63, wave = tid >> 6;
    const int row15 = lane & 15, quad = lane >> 4;
    const int j = jb * 16 + row15;

    if (grp == 0) {
        if (t > 0) block_wait(&c_h1[t - 1], 64);
    } else if (grp == 1) {
        block_wait(&c_h1[t], 64);
        if (t >= 4) block_wait(&c_h2[t - 4], 64);
    } else {
        block_wait(&g2f[t * 64 + jb], 1);
        if (t > 0) block_wait(&c_h2[t - 1], 64);
    }

    const __bf16* Ab = (grp == 0) ? h1s + (size_t)t * HB
                     : (grp == 1) ? h1s + (size_t)(t + 1) * HB
                                  : h2s + (size_t)t * HB;

    f32x4 a0 = {}, a1 = {}, a2 = {};
    const __bf16* ap = Ab + (size_t)(wave * 16 + row15) * HID + quad * 8;
    #pragma unroll 8
    for (int k = 0; k < HID; k += 32) {
        bf16x8 av = *(const bf16x8*)(ap + k);
        const __bf16* wp = W + (size_t)(((k >> 3) + quad) * 48 + row15) * 8;
        a0 = mfma16(av, *(const bf16x8*)(wp),       a0);
        a1 = mfma16(av, *(const bf16x8*)(wp + 128), a1);
        a2 = mfma16(av, *(const bf16x8*)(wp + 256), a2);
    }

    if (grp == 1) {
        float* op = gi2 + ((size_t)(t & 3) * NB + wave * 16 + quad * 4) * B3 + j;
        #pragma unroll
        for (int i = 0; i < 4; ++i) {
            op[(size_t)i * B3]           = a0[i];
            op[(size_t)i * B3 + HID]     = a1[i];
            op[(size_t)i * B3 + 2 * HID] = a2[i];
        }
        __syncthreads();
        if (tid == 0) {
            __threadfence();
            __hip_atomic_store(&g2f[t * 64 + jb], 1, __ATOMIC_RELEASE, __HIP_MEMORY_SCOPE_AGENT);
        }
        return;
    }

    const float* bh = (grp == 0) ? bhh1 : bhh2;
    const float b0 = bh[j], b1 = bh[HID + j], b2 = bh[2 * HID + j];
    __bf16* ho = ((grp == 0) ? h1s : h2s) + (size_t)(t + 1) * HB;

    #pragma unroll
    for (int i = 0; i < 4; ++i) {
        const int m = wave * 16 + quad * 4 + i;
        float gir, giz, gin;
        if (grp == 0) {
            if (t < TENC) {   // encoder: gi1 includes bih1
                const __bf16* pp = gi1 + ((size_t)t * NB + m) * B3 + j;
                gir = (float)pp[0]; giz = (float)pp[HID]; gin = (float)pp[2 * HID];
            } else {          // decoder: x = 0 -> gi = bih1
                gir = bih1[j]; giz = bih1[HID + j]; gin = bih1[2 * HID + j];
            }
        } else {
            const float* gp = gi2 + ((size_t)(t & 3) * NB + m) * B3 + j;
            gir = gp[0]; giz = gp[HID]; gin = gp[2 * HID];
            if (t < TENC) {   // encoder: word part zero -> add bih2
                gir += bih2[j]; giz += bih2[HID + j]; gin += bih2[2 * HID + j];
            } else {          // decoder: wproj includes word part + bih2
                const __bf16* pp = wproj + ((size_t)(t - TENC) * NB + m) * B3 + j;
                gir += (float)pp[0]; giz += (float)pp[HID]; gin += (float)pp[2 * HID];
            }
        }
        float r = 1.f / (1.f + expf(-(gir + a0[i] + b0)));
        float z = 1.f / (1.f + expf(-(giz + a1[i] + b1)));
        float n = tanhf(gin + r * (a2[i] + b2));
        float hov = (float)Ab[(size_t)m * HID + j];
        ho[(size_t)m * HID + j] = (__bf16)((1.f - z) * n + z * hov);
    }
    block_release((grp == 0) ? &c_h1[t] : &c_h2[t]);
}

__global__ __launch_bounds__(256, 1) void gru_chain(
    const float* __restrict__ Whh1, const float* __restrict__ Whh2, const float* __restrict__ Wih2,
    const float* __restrict__ bhh1, const float* __restrict__ bih1,
    const float* __restrict__ bhh2, const float* __restrict__ bih2,
    const __bf16* __restrict__ gi1, const __bf16* __restrict__ wproj,
    __bf16* __restrict__ h1s, __bf16* __restrict__ h2s, float* __restrict__ gi2,
    int* __restrict__ flags)
{
    __shared__ __align__(16) __bf16 W[48 * HID];   // 96 KiB -> 1 block/CU
    const int grp = blockIdx.x >> 6;
    const int jb  = blockIdx.x & 63;
    load_wslice(W, grp, jb * 16, Whh1, Whh2, Wih2);
    __syncthreads();
    int* c_h1 = flags;
    int* c_h2 = flags + 128;
    int* g2f  = flags + 256;
    for (int t = 0; t < TTOT; ++t)
        chain_step(grp, t, jb, W, bhh1, bih1, bhh2, bih2,
                   gi1, wproj, h1s, h2s, gi2, c_h1, c_h2, g2f);
}

// Fallback (no cooperative launch): one launch per phase; flags from prior launches
// are already set, so every block_wait exits immediately -> no deadlock.
__global__ __launch_bounds__(256, 1) void gru_chain_phase(
    int p,
    const float* __restrict__ Whh1, const float* __restrict__ Whh2, const float* __restrict__ Wih2,
    const float* __restrict__ bhh1, const float* __restrict__ bih1,
    const float* __restrict__ bhh2, const float* __restrict__ bih2,
    const __bf16* __restrict__ gi1, const __bf16* __restrict__ wproj,
    __bf16* __restrict__ h1s, __bf16* __restrict__ h2s, float* __restrict__ gi2,
    int* __restrict__ flags)
{
    __shared__ __align__(16) __bf16 W[48 * HID];
    const int grp = blockIdx.x >> 6;
    const int jb  = blockIdx.x & 63;
    const int t   = p - (grp == 1 ? 1 : grp == 2 ? 2 : 0);
    if (t < 0 || t >= TTOT) return;
    load_wslice(W, grp, jb * 16, Whh1, Whh2, Wih2);
    __syncthreads();
    chain_step(grp, t, jb, W, bhh1, bih1, bhh2, bih2,
               gi1, wproj, h1s, h2s, gi2, flags, flags + 128, flags + 256);
}

// ================= logits GEMM, Wout panel resident in LDS =================
// 500 blocks; block stages its 64-col Wout panel (bf16) into 128 KiB LDS ONCE
// (coalesced 2KB/wave-instr reads, XOR-swizzled tiles for conflict-free ds r/w),
// then sweeps all 27 m-tiles (3 per acc group). Out row remap: m=t*64+b -> b*27+t.
__global__ __launch_bounds__(256, 1) void out_gemm(
    const __bf16* __restrict__ A,   // 1728 x 1024 (decoder h2 slabs)
    const float* __restrict__ Bw,   // Wout 32000 x 1024
    const float* __restrict__ bias, // bout
    float* __restrict__ C)          // 1728 x 32000
{
    __shared__ __align__(16) __bf16 Bs[128 * 64 * 8];   // 128 KiB; tile = k8*64+col, ^ (k8&7)
    const int tid = threadIdx.x;
    const int n0 = blockIdx.x * 64;
    {
        const int row   = tid >> 7;      // 0..1 (panel col)
        const int chunk = tid & 127;     // k8: 8-float chunk within the 1024-K row
        const float* src0 = Bw + (size_t)(n0 + row) * HID + chunk * 8;
        #pragma unroll 4
        for (int i = 0; i < 32; ++i) {   // rows 2i+row
            const float* s = src0 + (size_t)i * 2 * HID;
            float4 u = *(const float4*)s;
            float4 v = *(const float4*)(s + 4);
            int col  = i * 2 + row;
            int tile = (chunk * 64 + col) ^ (chunk & 7);
            *(bf16x8*)&Bs[(size_t)tile * 8] = cvt8v(u, v);
        }
    }
    __syncthreads();
    const int lane = tid & 63, wave = tid >> 6;
    const int row15 = lane & 15, quad = lane >> 4;
    float bn[4];
    #pragma unroll
    for (int ns = 0; ns < 4; ++ns) bn[ns] = bias[n0 + ns * 16 + row15];

    for (int mg = 0; mg < 9; ++mg) {     // 9 groups x 3 m-tiles = 27
        f32x4 acc[3][4] = {};
        const __bf16* ap = A + (size_t)(mg * 192 + wave * 16 + row15) * HID + quad * 8;
        #pragma unroll 2
        for (int k = 0; k < HID; k += 32) {
            const int k8q = (k >> 3) + quad;
            const __bf16* bp = &Bs[(size_t)((k8q * 64 + row15) ^ (k8q & 7)) * 8];
            bf16x8 b0 = *(const bf16x8*)(bp);
            bf16x8 b1 = *(const bf16x8*)(bp + 128);
            bf16x8 b2 = *(const bf16x8*)(bp + 256);
            bf16x8 b3 = *(const bf16x8*)(bp + 384);
            #pragma unroll
            for (int mi = 0; mi < 3; ++mi) {
                bf16x8 av = *(const bf16x8*)(ap + (size_t)mi * 64 * HID + k);
                acc[mi][0] = mfma16(av, b0, acc[mi][0]);
                acc[mi][1] = mfma16(av, b1, acc[mi][1]);
                acc[mi][2] = mfma16(av, b2, acc[mi][2]);
                acc[mi][3] = mfma16(av, b3, acc[mi][3]);
            }
        }
        #pragma unroll
        for (int mi = 0; mi < 3; ++mi) {
            const int mt = mg * 3 + mi;
            #pragma unroll
            for (int ns = 0; ns < 4; ++ns)
                #pragma unroll
                for (int i = 0; i < 4; ++i) {
                    const int b = wave * 16 + quad * 4 + i;
                    C[(size_t)(b * TDEC + mt) * VOC + n0 + ns * 16 + row15] = acc[mi][ns][i] + bn[ns];
                }
        }
    }
}

// ---------- in-place row log-softmax over 32000 f32 cols ----------
__global__ __launch_bounds__(256) void logsoftmax_rows(float* __restrict__ out) {
    const int r = blockIdx.x;
    float* p = out + (size_t)r * VOC;
    const int tid = threadIdx.x;
    const int lane = tid & 63, wid = tid >> 6;
    __shared__ float red[4];
    __shared__ float bc[2];

    float mx = -3.0e38f;
    for (int c = tid; c < VOC / 4; c += 256) {
        float4 v = ((const float4*)p)[c];
        mx = fmaxf(mx, fmaxf(fmaxf(v.x, v.y), fmaxf(v.z, v.w)));
    }
    #pragma unroll
    for (int o = 32; o > 0; o >>= 1) mx = fmaxf(mx, __shfl_down(mx, o));
    if (lane == 0) red[wid] = mx;
    __syncthreads();
    if (tid == 0) bc[0] = fmaxf(fmaxf(red[0], red[1]), fmaxf(red[2], red[3]));
    __syncthreads();
    mx = bc[0];

    float s = 0.f;
    for (int c = tid; c < VOC / 4; c += 256) {
        float4 v = ((const float4*)p)[c];
        s += expf(v.x - mx) + expf(v.y - mx) + expf(v.z - mx) + expf(v.w - mx);
    }
    #pragma unroll
    for (int o = 32; o > 0; o >>= 1) s += __shfl_down(s, o);
    if (lane == 0) red[wid] = s;
    __syncthreads();
    if (tid == 0) bc[1] = mx + logf(red[0] + red[1] + red[2] + red[3]);
    __syncthreads();
    const float C = bc[1];

    for (int c = tid; c < VOC / 4; c += 256) {
        float4 v = ((const float4*)p)[c];
        v.x -= C; v.y -= C; v.z -= C; v.w -= C;
        ((float4*)p)[c] = v;
    }
}

// ---------- launch ----------
extern "C" void kernel_launch(void* const* d_in, const int* in_sizes, int n_in,
                              void* d_out, int out_size, void* d_ws, size_t ws_size,
                              hipStream_t stream) {
    const float* vid  = (const float*)d_in[0];
    const int*   tgt  = (const int*)d_in[1];
    const float* emb  = (const float*)d_in[2];
    const float* Wih1 = (const float*)d_in[3];
    const float* Whh1 = (const float*)d_in[4];
    const float* bih1 = (const float*)d_in[5];
    const float* bhh1 = (const float*)d_in[6];
    const float* Wih2 = (const float*)d_in[7];
    const float* Whh2 = (const float*)d_in[8];
    const float* bih2 = (const float*)d_in[9];
    const float* bhh2 = (const float*)d_in[10];
    const float* Wout = (const float*)d_in[11];
    const float* bout = (const float*)d_in[12];
    float* out = (float*)d_out;

    char* w = (char*)d_ws;
    __bf16* h1s   = (__bf16*)w; w += (size_t)68 * HB * 2;           // 68 slabs (slab0 = zeros)
    __bf16* h2s   = (__bf16*)w; w += (size_t)68 * HB * 2;
    float*  gi2   = (float*)w;  w += (size_t)4 * NB * B3 * 4;       // 4-deep ring, f32
    __bf16* gi1   = (__bf16*)w; w += (size_t)TENC * NB * B3 * 2;    // 40x64x3072
    __bf16* wproj = (__bf16*)w; w += (size_t)TDEC * NB * B3 * 2;    // 27x64x3072 (incl. bih2)
    __bf16* words = (__bf16*)w; w += (size_t)TDEC * NB * 512 * 2;
    int*    flags = (int*)w;    w += (size_t)NFLAG * 4;             // c_h1[128] c_h2[128] g2f[...]

    zero_h<<<256, 256, 0, stream>>>(h1s, h2s, flags);

    // gi1[t*64+b][:] = vid[b][t][:] @ Wih1^T + bih1   (m=b*40+t -> orow=(m%40)*64+m/40)
    gemm_bt<float, true><<<dim3(TENC, 48), 256, 0, stream>>>(
        vid, 2048, Wih1, 2048, bih1, gi1, B3, 2048, TENC, 64, 1);

    gather_words<<<TDEC * NB, 64, 0, stream>>>(emb, tgt, words);

    // wproj[t*64+b][:] = words row @ Wih2[:,1024:]^T + bih2
    gemm_bt<__bf16, true><<<dim3(TDEC, 48), 256, 0, stream>>>(
        words, 512, Wih2 + 1024, 1536, bih2, wproj, B3, 512, 1 << 30, 1, 0);

    static int coop = -1;
    if (coop < 0) {
        int dev = 0; (void)hipGetDevice(&dev);
        int v = 0;
        if (hipDeviceGetAttribute(&v, hipDeviceAttributeCooperativeLaunch, dev) != hipSuccess) v = 0;
        coop = v;
    }
    bool launched = false;
    if (coop) {
        void* cargs[] = {(void*)&Whh1, (void*)&Whh2, (void*)&Wih2,
                         (void*)&bhh1, (void*)&bih1, (void*)&bhh2, (void*)&bih2,
                         (void*)&gi1, (void*)&wproj,
                         (void*)&h1s, (void*)&h2s, (void*)&gi2, (void*)&flags};
        launched = (hipLaunchCooperativeKernel((void*)gru_chain, dim3(192), dim3(256),
                                               cargs, 0, stream) == hipSuccess);
    }
    if (!launched) {
        for (int p = 0; p < TTOT + 2; ++p)
            gru_chain_phase<<<192, 256, 0, stream>>>(p, Whh1, Whh2, Wih2,
                                                     bhh1, bih1, bhh2, bih2,
                                                     gi1, wproj, h1s, h2s, gi2, flags);
    }

    // logits: decoder h2 slabs (41..67) @ Wout^T + bout -> out rows b*27+t
    out_gemm<<<500, 256, 0, stream>>>(h2s + (size_t)41 * HB, Wout, bout, out);

    logsoftmax_rows<<<TDEC * NB, 256, 0, stream>>>(out);
}

// Round 3
// 2412.997 us; speedup vs baseline: 1.3848x; 1.2977x over previous
//
#include <hip/hip_runtime.h>
#include <hip/hip_cooperative_groups.h>

namespace cg = cooperative_groups;

// ---------- types ----------
using bf16x8 = __attribute__((ext_vector_type(8))) __bf16;
using f32x4  = __attribute__((ext_vector_type(4))) float;

__device__ __forceinline__ f32x4 mfma16(bf16x8 a, bf16x8 b, f32x4 c) {
    return __builtin_amdgcn_mfma_f32_16x16x32_bf16(a, b, c, 0, 0, 0);
}

__device__ __forceinline__ bf16x8 cvt8v(float4 u, float4 v) {
    bf16x8 r;
    r[0] = (__bf16)u.x; r[1] = (__bf16)u.y; r[2] = (__bf16)u.z; r[3] = (__bf16)u.w;
    r[4] = (__bf16)v.x; r[5] = (__bf16)v.y; r[6] = (__bf16)v.z; r[7] = (__bf16)v.w;
    return r;
}

// ---------- constants ----------
#define HID   1024
#define B3    3072
#define NB    64      // batch
#define TENC  40
#define TDEC  27
#define TTOT  67      // TENC + TDEC
#define VOC   32000
#define HB    65536   // NB * HID
#define NFLAG 8192
#define WSTR  50      // padded LDS tile stride (48 rows + 2 pad) -> conflict-free quad reads

// ---------- flag sync primitives ----------
// Release: __syncthreads() drains all threads' stores to L2 (compiler emits vmcnt(0)
// before s_barrier); thread0's RELEASE atomic performs the agent-scope writeback.
__device__ __forceinline__ void block_release(int* f) {
    __syncthreads();
    if (threadIdx.x == 0)
        __hip_atomic_fetch_add(f, 1, __ATOMIC_RELEASE, __HIP_MEMORY_SCOPE_AGENT);
}
// Wait: RELAXED polling (no per-poll L2 invalidate), ONE acquire once satisfied.
// Each wave leader polls so every SIMD's path is ordered; __syncthreads broadcasts.
__device__ __forceinline__ void block_wait2(int* f1, int tgt1, int* f2, int tgt2) {
    if ((threadIdx.x & 63) == 0) {
        while (__hip_atomic_load(f1, __ATOMIC_RELAXED, __HIP_MEMORY_SCOPE_AGENT) < tgt1)
            __builtin_amdgcn_s_sleep(1);
        if (f2)
            while (__hip_atomic_load(f2, __ATOMIC_RELAXED, __HIP_MEMORY_SCOPE_AGENT) < tgt2)
                __builtin_amdgcn_s_sleep(1);
        (void)__hip_atomic_load(f1, __ATOMIC_ACQUIRE, __HIP_MEMORY_SCOPE_AGENT);
    }
    __syncthreads();
}

// ---------- zero init of h1(-1), h2(-1) slabs + sync flags ----------
__global__ __launch_bounds__(256) void zero_h(__bf16* __restrict__ h1, __bf16* __restrict__ h2,
                                              int* __restrict__ flags) {
    int i = blockIdx.x * 256 + threadIdx.x;   // 65536 threads
    h1[i] = (__bf16)0.f;
    h2[i] = (__bf16)0.f;
    if (i < NFLAG) flags[i] = 0;
}

// ---------- word gather: words[t*64+b][:] = bf16(emb[tgt[b][t]][:]) ----------
__global__ __launch_bounds__(64) void gather_words(const float* __restrict__ emb,
                                                   const int* __restrict__ tgt,
                                                   __bf16* __restrict__ words) {
    int row = blockIdx.x;            // 0..1727  = t*64 + b
    int b = row & 63, t = row >> 6;
    int idx = tgt[b * 28 + t];
    const float* src = emb + (size_t)idx * 512 + threadIdx.x * 8;
    float4 u = *(const float4*)src;
    float4 v = *(const float4*)(src + 4);
    *(bf16x8*)(words + (size_t)row * 512 + threadIdx.x * 8) = cvt8v(u, v);
}

// ---------- tiled GEMM: C = A(MxK) @ B(NxK)^T + bias  (used for gi1, wproj) ----------
template <typename TA, bool OUTBF>
__global__ __launch_bounds__(256) void gemm_bt(
    const TA* __restrict__ A, int lda,
    const float* __restrict__ Bw, int ldb,
    const float* __restrict__ bias,
    void* __restrict__ Cout, int ldc,
    int K, int mdiv, int ms1, int ms2)
{
    __shared__ __align__(16) __bf16 As[64][40];
    __shared__ __align__(16) __bf16 Bs[64][40];
    const int tid  = threadIdx.x;
    const int m0   = blockIdx.x * 64;
    const int n0   = blockIdx.y * 64;
    const int srow = tid >> 2;
    const int sseg = (tid & 3) * 8;
    const TA*    ga = A  + (size_t)(m0 + srow) * lda + sseg;
    const float* gb = Bw + (size_t)(n0 + srow) * ldb + sseg;
    const int lane  = tid & 63, wave = tid >> 6;
    const int wm    = (wave >> 1) * 32, wn = (wave & 1) * 32;
    const int row15 = lane & 15, quad = lane >> 4;

    f32x4 acc[2][2] = {};
    for (int k = 0; k < K; k += 32) {
        __syncthreads();
        if constexpr (__is_same(TA, float)) {
            float4 u = *(const float4*)(ga + k);
            float4 v = *(const float4*)(ga + k + 4);
            *(bf16x8*)&As[srow][sseg] = cvt8v(u, v);
        } else {
            *(bf16x8*)&As[srow][sseg] = *(const bf16x8*)(ga + k);
        }
        {
            float4 u = *(const float4*)(gb + k);
            float4 v = *(const float4*)(gb + k + 4);
            *(bf16x8*)&Bs[srow][sseg] = cvt8v(u, v);
        }
        __syncthreads();
        bf16x8 a0 = *(const bf16x8*)&As[wm + row15][quad * 8];
        bf16x8 a1 = *(const bf16x8*)&As[wm + 16 + row15][quad * 8];
        bf16x8 b0 = *(const bf16x8*)&Bs[wn + row15][quad * 8];
        bf16x8 b1 = *(const bf16x8*)&Bs[wn + 16 + row15][quad * 8];
        acc[0][0] = mfma16(a0, b0, acc[0][0]);
        acc[0][1] = mfma16(a0, b1, acc[0][1]);
        acc[1][0] = mfma16(a1, b0, acc[1][0]);
        acc[1][1] = mfma16(a1, b1, acc[1][1]);
    }
    #pragma unroll
    for (int mt = 0; mt < 2; ++mt)
        #pragma unroll
        for (int nt = 0; nt < 2; ++nt)
            #pragma unroll
            for (int i = 0; i < 4; ++i) {
                int m = m0 + wm + mt * 16 + quad * 4 + i;
                int n = n0 + wn + nt * 16 + row15;
                int orow = (m % mdiv) * ms1 + (m / mdiv) * ms2;
                float v = acc[mt][nt][i] + bias[n];
                if constexpr (OUTBF)
                    ((__bf16*)Cout)[(size_t)orow * ldc + n] = (__bf16)v;
                else
                    ((float*)Cout)[(size_t)orow * ldc + n] = v;
            }
}

// ================= persistent GRU chain (flag-paced pipeline) =================
// 192 blocks, 3 groups of 64. Block (grp, jb) owns hidden cols [jb*16, jb*16+16).
//   grp 0: h1 chain with Whh1       (step t: reads h1 slab t, writes slab t+1)
//   grp 1: gi2(t) = h1(t) @ Wih2[:, :1024]^T  -> f32 ring slot t&3
//   grp 2: h2 chain with Whh2       (step t: reads h2 slab t + gi2 slot, writes slab t+1)
// Per-step body is fully latency-optimized: whole 128KB A-slab prefetched into
// 128 VGPRs (32 outstanding dwordx4 loads/thread), gate inputs hoisted.

__device__ __forceinline__ void load_wslice(
    __bf16* W, int grp, int j0,
    const float* __restrict__ Whh1, const float* __restrict__ Whh2,
    const float* __restrict__ Wih2)
{
    const int tid = threadIdx.x;
    const float* src = (grp == 0) ? Whh1 : (grp == 1) ? Wih2 : Whh2;
    const int ld = (grp == 1) ? 1536 : 1024;
    #pragma unroll 4
    for (int i = 0; i < 24; ++i) {
        int tile = i * 256 + tid;               // 6144 tiles
        int r48 = tile >> 7, k8 = tile & 127;
        int srow = (r48 >> 4) * HID + j0 + (r48 & 15);
        const float* pp = src + (size_t)srow * ld + k8 * 8;
        float4 u = *(const float4*)pp;
        float4 v = *(const float4*)(pp + 4);
        *(bf16x8*)&W[(size_t)(k8 * WSTR + r48) * 8] = cvt8v(u, v);
    }
}

__device__ __forceinline__ void chain_step(
    int grp, int t, int jb, const __bf16* __restrict__ W,
    const float* __restrict__ bhh1, const float* __restrict__ bih1,
    const float* __restrict__ bhh2, const float* __restrict__ bih2,
    const __bf16* __restrict__ gi1, const __bf16* __restrict__ wproj,
    __bf16* __restrict__ h1s, __bf16* __restrict__ h2s, float* __restrict__ gi2,
    int* __restrict__ c_h1, int* __restrict__ c_h2, int* __restrict__ g2f)
{
    const int tid = threadIdx.x;
    const int lane = tid & 63, wave = tid >> 6;
    const int row15 = lane & 15, quad = lane >> 4;
    const int j = jb * 16 + row15;

    if (grp == 0) {
        if (t > 0) block_wait2(&c_h1[t - 1], 64, nullptr, 0);
    } else if (grp == 1) {
        block_wait2(&c_h1[t], 64, (t >= 4) ? &c_h2[t - 4] : nullptr, 64);
    } else {
        block_wait2(&g2f[t * 64 + jb], 1, (t > 0) ? &c_h2[t - 1] : nullptr, 64);
    }

    const __bf16* Ab = (grp == 0) ? h1s + (size_t)t * HB
                     : (grp == 1) ? h1s + (size_t)(t + 1) * HB
                                  : h2s + (size_t)t * HB;

    // ---- full-slab register prefetch: 32 x dwordx4, all in flight ----
    const __bf16* ap = Ab + (size_t)(wave * 16 + row15) * HID + quad * 8;
    bf16x8 areg[32];
    #pragma unroll
    for (int kk = 0; kk < 32; ++kk)
        areg[kk] = *(const bf16x8*)(ap + kk * 32);

    // ---- hoisted gate inputs + h_old (issue while slab loads are in flight) ----
    float gr[4], gz[4], gn[4], hov[4];
    if (grp == 0) {
        if (t < TENC) {
            #pragma unroll
            for (int i = 0; i < 4; ++i) {
                const int m = wave * 16 + quad * 4 + i;
                const __bf16* pp = gi1 + ((size_t)t * NB + m) * B3 + j;
                gr[i] = (float)pp[0]; gz[i] = (float)pp[HID]; gn[i] = (float)pp[2 * HID];
            }
        } else {
            const float r0 = bih1[j], z0 = bih1[HID + j], n0 = bih1[2 * HID + j];
            #pragma unroll
            for (int i = 0; i < 4; ++i) { gr[i] = r0; gz[i] = z0; gn[i] = n0; }
        }
    } else if (grp == 2) {
        #pragma unroll
        for (int i = 0; i < 4; ++i) {
            const int m = wave * 16 + quad * 4 + i;
            const float* gp = gi2 + ((size_t)(t & 3) * NB + m) * B3 + j;
            gr[i] = gp[0]; gz[i] = gp[HID]; gn[i] = gp[2 * HID];
        }
        if (t < TENC) {
            const float r0 = bih2[j], z0 = bih2[HID + j], n0 = bih2[2 * HID + j];
            #pragma unroll
            for (int i = 0; i < 4; ++i) { gr[i] += r0; gz[i] += z0; gn[i] += n0; }
        } else {
            #pragma unroll
            for (int i = 0; i < 4; ++i) {
                const int m = wave * 16 + quad * 4 + i;
                const __bf16* pp = wproj + ((size_t)(t - TENC) * NB + m) * B3 + j;
                gr[i] += (float)pp[0]; gz[i] += (float)pp[HID]; gn[i] += (float)pp[2 * HID];
            }
        }
    }
    if (grp != 1) {
        #pragma unroll
        for (int i = 0; i < 4; ++i) {
            const int m = wave * 16 + quad * 4 + i;
            hov[i] = (float)Ab[(size_t)m * HID + j];
        }
    }

    // ---- MFMA sweep from registers + LDS weights ----
    f32x4 a0 = {}, a1 = {}, a2 = {};
    #pragma unroll
    for (int kk = 0; kk < 32; ++kk) {
        const __bf16* wp = W + (size_t)((kk * 4 + quad) * WSTR + row15) * 8;
        a0 = mfma16(areg[kk], *(const bf16x8*)(wp),           a0);
        a1 = mfma16(areg[kk], *(const bf16x8*)(wp + 16 * 8),  a1);
        a2 = mfma16(areg[kk], *(const bf16x8*)(wp + 32 * 8),  a2);
    }

    if (grp == 1) {
        float* op = gi2 + ((size_t)(t & 3) * NB + wave * 16 + quad * 4) * B3 + j;
        #pragma unroll
        for (int i = 0; i < 4; ++i) {
            op[(size_t)i * B3]           = a0[i];
            op[(size_t)i * B3 + HID]     = a1[i];
            op[(size_t)i * B3 + 2 * HID] = a2[i];
        }
        __syncthreads();
        if (tid == 0)
            __hip_atomic_store(&g2f[t * 64 + jb], 1, __ATOMIC_RELEASE, __HIP_MEMORY_SCOPE_AGENT);
        return;
    }

    const float* bh = (grp == 0) ? bhh1 : bhh2;
    const float b0 = bh[j], b1 = bh[HID + j], b2 = bh[2 * HID + j];
    __bf16* ho = ((grp == 0) ? h1s : h2s) + (size_t)(t + 1) * HB;

    #pragma unroll
    for (int i = 0; i < 4; ++i) {
        const int m = wave * 16 + quad * 4 + i;
        float r = 1.f / (1.f + expf(-(gr[i] + a0[i] + b0)));
        float z = 1.f / (1.f + expf(-(gz[i] + a1[i] + b1)));
        float n = tanhf(gn[i] + r * (a2[i] + b2));
        ho[(size_t)m * HID + j] = (__bf16)((1.f - z) * n + z * hov[i]);
    }
    block_release((grp == 0) ? &c_h1[t] : &c_h2[t]);
}

__global__ __launch_bounds__(256, 1) void gru_chain(
    const float* __restrict__ Whh1, const float* __restrict__ Whh2, const float* __restrict__ Wih2,
    const float* __restrict__ bhh1, const float* __restrict__ bih1,
    const float* __restrict__ bhh2, const float* __restrict__ bih2,
    const __bf16* __restrict__ gi1, const __bf16* __restrict__ wproj,
    __bf16* __restrict__ h1s, __bf16* __restrict__ h2s, float* __restrict__ gi2,
    int* __restrict__ flags)
{
    __shared__ __align__(16) __bf16 W[128 * WSTR * 8];   // 100 KiB -> 1 block/CU
    const int grp = blockIdx.x >> 6;
    const int jb  = blockIdx.x & 63;
    load_wslice(W, grp, jb * 16, Whh1, Whh2, Wih2);
    __syncthreads();
    int* c_h1 = flags;
    int* c_h2 = flags + 128;
    int* g2f  = flags + 256;
    for (int t = 0; t < TTOT; ++t)
        chain_step(grp, t, jb, W, bhh1, bih1, bhh2, bih2,
                   gi1, wproj, h1s, h2s, gi2, c_h1, c_h2, g2f);
}

// Fallback (no cooperative launch): one launch per phase; flags from prior launches
// are already set, so every block_wait exits immediately -> no deadlock.
__global__ __launch_bounds__(256, 1) void gru_chain_phase(
    int p,
    const float* __restrict__ Whh1, const float* __restrict__ Whh2, const float* __restrict__ Wih2,
    const float* __restrict__ bhh1, const float* __restrict__ bih1,
    const float* __restrict__ bhh2, const float* __restrict__ bih2,
    const __bf16* __restrict__ gi1, const __bf16* __restrict__ wproj,
    __bf16* __restrict__ h1s, __bf16* __restrict__ h2s, float* __restrict__ gi2,
    int* __restrict__ flags)
{
    __shared__ __align__(16) __bf16 W[128 * WSTR * 8];
    const int grp = blockIdx.x >> 6;
    const int jb  = blockIdx.x & 63;
    const int t   = p - (grp == 1 ? 1 : grp == 2 ? 2 : 0);
    if (t < 0 || t >= TTOT) return;
    load_wslice(W, grp, jb * 16, Whh1, Whh2, Wih2);
    __syncthreads();
    chain_step(grp, t, jb, W, bhh1, bih1, bhh2, bih2,
               gi1, wproj, h1s, h2s, gi2, flags, flags + 128, flags + 256);
}

// ================= logits GEMM, Wout panel resident in LDS =================
__global__ __launch_bounds__(256, 1) void out_gemm(
    const __bf16* __restrict__ A,   // 1728 x 1024 (decoder h2 slabs)
    const float* __restrict__ Bw,   // Wout 32000 x 1024
    const float* __restrict__ bias, // bout
    float* __restrict__ C)          // 1728 x 32000
{
    __shared__ __align__(16) __bf16 Bs[128 * 64 * 8];   // 128 KiB; tile = k8*64+col, ^ (k8&7)
    const int tid = threadIdx.x;
    const int n0 = blockIdx.x * 64;
    {
        const int row   = tid >> 7;      // 0..1 (panel col)
        const int chunk = tid & 127;     // k8: 8-float chunk within the 1024-K row
        const float* src0 = Bw + (size_t)(n0 + row) * HID + chunk * 8;
        #pragma unroll 4
        for (int i = 0; i < 32; ++i) {   // rows 2i+row
            const float* s = src0 + (size_t)i * 2 * HID;
            float4 u = *(const float4*)s;
            float4 v = *(const float4*)(s + 4);
            int col  = i * 2 + row;
            int tile = (chunk * 64 + col) ^ (chunk & 7);
            *(bf16x8*)&Bs[(size_t)tile * 8] = cvt8v(u, v);
        }
    }
    __syncthreads();
    const int lane = tid & 63, wave = tid >> 6;
    const int row15 = lane & 15, quad = lane >> 4;
    float bn[4];
    #pragma unroll
    for (int ns = 0; ns < 4; ++ns) bn[ns] = bias[n0 + ns * 16 + row15];

    for (int mg = 0; mg < 9; ++mg) {     // 9 groups x 3 m-tiles = 27
        f32x4 acc[3][4] = {};
        const __bf16* ap = A + (size_t)(mg * 192 + wave * 16 + row15) * HID + quad * 8;
        #pragma unroll 2
        for (int k = 0; k < HID; k += 32) {
            const int k8q = (k >> 3) + quad;
            const __bf16* bp = &Bs[(size_t)((k8q * 64 + row15) ^ (k8q & 7)) * 8];
            bf16x8 b0 = *(const bf16x8*)(bp);
            bf16x8 b1 = *(const bf16x8*)(bp + 128);
            bf16x8 b2 = *(const bf16x8*)(bp + 256);
            bf16x8 b3 = *(const bf16x8*)(bp + 384);
            #pragma unroll
            for (int mi = 0; mi < 3; ++mi) {
                bf16x8 av = *(const bf16x8*)(ap + (size_t)mi * 64 * HID + k);
                acc[mi][0] = mfma16(av, b0, acc[mi][0]);
                acc[mi][1] = mfma16(av, b1, acc[mi][1]);
                acc[mi][2] = mfma16(av, b2, acc[mi][2]);
                acc[mi][3] = mfma16(av, b3, acc[mi][3]);
            }
        }
        #pragma unroll
        for (int mi = 0; mi < 3; ++mi) {
            const int mt = mg * 3 + mi;
            #pragma unroll
            for (int ns = 0; ns < 4; ++ns)
                #pragma unroll
                for (int i = 0; i < 4; ++i) {
                    const int b = wave * 16 + quad * 4 + i;
                    C[(size_t)(b * TDEC + mt) * VOC + n0 + ns * 16 + row15] = acc[mi][ns][i] + bn[ns];
                }
        }
    }
}

// ---------- in-place row log-softmax over 32000 f32 cols ----------
__global__ __launch_bounds__(256) void logsoftmax_rows(float* __restrict__ out) {
    const int r = blockIdx.x;
    float* p = out + (size_t)r * VOC;
    const int tid = threadIdx.x;
    const int lane = tid & 63, wid = tid >> 6;
    __shared__ float red[4];
    __shared__ float bc[2];

    float mx = -3.0e38f;
    for (int c = tid; c < VOC / 4; c += 256) {
        float4 v = ((const float4*)p)[c];
        mx = fmaxf(mx, fmaxf(fmaxf(v.x, v.y), fmaxf(v.z, v.w)));
    }
    #pragma unroll
    for (int o = 32; o > 0; o >>= 1) mx = fmaxf(mx, __shfl_down(mx, o));
    if (lane == 0) red[wid] = mx;
    __syncthreads();
    if (tid == 0) bc[0] = fmaxf(fmaxf(red[0], red[1]), fmaxf(red[2], red[3]));
    __syncthreads();
    mx = bc[0];

    float s = 0.f;
    for (int c = tid; c < VOC / 4; c += 256) {
        float4 v = ((const float4*)p)[c];
        s += expf(v.x - mx) + expf(v.y - mx) + expf(v.z - mx) + expf(v.w - mx);
    }
    #pragma unroll
    for (int o = 32; o > 0; o >>= 1) s += __shfl_down(s, o);
    if (lane == 0) red[wid] = s;
    __syncthreads();
    if (tid == 0) bc[1] = mx + logf(red[0] + red[1] + red[2] + red[3]);
    __syncthreads();
    const float C = bc[1];

    for (int c = tid; c < VOC / 4; c += 256) {
        float4 v = ((const float4*)p)[c];
        v.x -= C; v.y -= C; v.z -= C; v.w -= C;
        ((float4*)p)[c] = v;
    }
}

// ---------- launch ----------
extern "C" void kernel_launch(void* const* d_in, const int* in_sizes, int n_in,
                              void* d_out, int out_size, void* d_ws, size_t ws_size,
                              hipStream_t stream) {
    const float* vid  = (const float*)d_in[0];
    const int*   tgt  = (const int*)d_in[1];
    const float* emb  = (const float*)d_in[2];
    const float* Wih1 = (const float*)d_in[3];
    const float* Whh1 = (const float*)d_in[4];
    const float* bih1 = (const float*)d_in[5];
    const float* bhh1 = (const float*)d_in[6];
    const float* Wih2 = (const float*)d_in[7];
    const float* Whh2 = (const float*)d_in[8];
    const float* bih2 = (const float*)d_in[9];
    const float* bhh2 = (const float*)d_in[10];
    const float* Wout = (const float*)d_in[11];
    const float* bout = (const float*)d_in[12];
    float* out = (float*)d_out;

    char* w = (char*)d_ws;
    __bf16* h1s   = (__bf16*)w; w += (size_t)68 * HB * 2;           // 68 slabs (slab0 = zeros)
    __bf16* h2s   = (__bf16*)w; w += (size_t)68 * HB * 2;
    float*  gi2   = (float*)w;  w += (size_t)4 * NB * B3 * 4;       // 4-deep ring, f32
    __bf16* gi1   = (__bf16*)w; w += (size_t)TENC * NB * B3 * 2;    // 40x64x3072
    __bf16* wproj = (__bf16*)w; w += (size_t)TDEC * NB * B3 * 2;    // 27x64x3072 (incl. bih2)
    __bf16* words = (__bf16*)w; w += (size_t)TDEC * NB * 512 * 2;
    int*    flags = (int*)w;    w += (size_t)NFLAG * 4;             // c_h1[128] c_h2[128] g2f[...]

    zero_h<<<256, 256, 0, stream>>>(h1s, h2s, flags);

    // gi1[t*64+b][:] = vid[b][t][:] @ Wih1^T + bih1   (m=b*40+t -> orow=(m%40)*64+m/40)
    gemm_bt<float, true><<<dim3(TENC, 48), 256, 0, stream>>>(
        vid, 2048, Wih1, 2048, bih1, gi1, B3, 2048, TENC, 64, 1);

    gather_words<<<TDEC * NB, 64, 0, stream>>>(emb, tgt, words);

    // wproj[t*64+b][:] = words row @ Wih2[:,1024:]^T + bih2
    gemm_bt<__bf16, true><<<dim3(TDEC, 48), 256, 0, stream>>>(
        words, 512, Wih2 + 1024, 1536, bih2, wproj, B3, 512, 1 << 30, 1, 0);

    static int coop = -1;
    if (coop < 0) {
        int dev = 0; (void)hipGetDevice(&dev);
        int v = 0;
        if (hipDeviceGetAttribute(&v, hipDeviceAttributeCooperativeLaunch, dev) != hipSuccess) v = 0;
        coop = v;
    }
    bool launched = false;
    if (coop) {
        void* cargs[] = {(void*)&Whh1, (void*)&Whh2, (void*)&Wih2,
                         (void*)&bhh1, (void*)&bih1, (void*)&bhh2, (void*)&bih2,
                         (void*)&gi1, (void*)&wproj,
                         (void*)&h1s, (void*)&h2s, (void*)&gi2, (void*)&flags};
        launched = (hipLaunchCooperativeKernel((void*)gru_chain, dim3(192), dim3(256),
                                               cargs, 0, stream) == hipSuccess);
    }
    if (!launched) {
        for (int p = 0; p < TTOT + 2; ++p)
            gru_chain_phase<<<192, 256, 0, stream>>>(p, Whh1, Whh2, Wih2,
                                                     bhh1, bih1, bhh2, bih2,
                                                     gi1, wproj, h1s, h2s, gi2, flags);
    }

    // logits: decoder h2 slabs (41..67) @ Wout^T + bout -> out rows b*27+t
    out_gemm<<<500, 256, 0, stream>>>(h2s + (size_t)41 * HB, Wout, bout, out);

    logsoftmax_rows<<<TDEC * NB, 256, 0, stream>>>(out);
}